// Round 16
// baseline (424.681 us; speedup 1.0000x reference)
//
#include <hip/hip_runtime.h>
#include <hip/hip_bf16.h>

typedef __attribute__((ext_vector_type(8))) short short8;
typedef __attribute__((ext_vector_type(4))) float f32x4;
typedef __attribute__((ext_vector_type(2))) float f32x2;
typedef __attribute__((ext_vector_type(4))) int int32x4;

// raw buffer load: 32-bit voffset addressing (no per-lane 64-bit addr VALU).
__device__ unsigned int llvm_amdgcn_raw_buffer_load_u32(int32x4 srsrc, int voffset,
                                                        int soffset, int aux)
    __asm("llvm.amdgcn.raw.buffer.load.i32");

#define VOXELS 262144  // 64^3
#define ZC_PAD 264
#define Z0_PAD 72
#define Z2_PAD 520
#define Z3_PAD 264
#define NCELL  512     // 8x8x8 Morton cells

// ---------------- volume transpose: (C,D,H,W) -> (D,H,W,C) ----------------
template <bool VT16>
__global__ void k_transpose(const float* __restrict__ v0, const float* __restrict__ v1,
                            const float* __restrict__ v2, const float* __restrict__ v3,
                            void* __restrict__ vtp) {
    int b  = blockIdx.x;
    int q  = b >> 12;
    int zy = b & 4095;
    const float* src = (q == 0) ? v0 : (q == 1) ? v1 : (q == 2) ? v2 : v3;
    __shared__ float buf[32][65];
    int t = threadIdx.x;
    int x = t & 63, c0 = t >> 6;
    for (int cp = 0; cp < 32; cp += 4) {
        int c = c0 + cp;
        buf[c][x] = src[(size_t)c * VOXELS + (size_t)zy * 64 + x];
    }
    __syncthreads();
    const size_t base = ((size_t)q * VOXELS + (size_t)zy * 64) * 32;
    if (VT16) {
        // dword stores (2 bf16 channels/thread) -> 256 B contiguous per wave instr
        const int cp2 = t & 15;       // channel pair
        const int xg  = t >> 4;       // 16 x-positions per pass
        unsigned* dstw = (unsigned*)((__hip_bfloat16*)vtp + base);
        for (int xx = xg; xx < 64; xx += 16) {
            __hip_bfloat16 h0 = __float2bfloat16(buf[cp2 * 2][xx]);
            __hip_bfloat16 h1 = __float2bfloat16(buf[cp2 * 2 + 1][xx]);
            unsigned u = ((unsigned)*(unsigned short*)&h1 << 16) | *(unsigned short*)&h0;
            dstw[xx * 16 + cp2] = u;
        }
    } else {
        int c = t & 31, xg = t >> 5;
        for (int xx = xg; xx < 64; xx += 8) {
            ((float*)vtp)[base + xx * 32 + c] = buf[c][xx];
        }
    }
}

// ------------- merged weight pack: all 5 weight tensors in ONE launch -------------
__device__ __forceinline__ void prep_one(const float* __restrict__ W,
                                         __hip_bfloat16* __restrict__ wf,
                                         int K, int mode, int n) {
    int e = n & 7, lane = (n >> 3) & 63;
    int rest = n >> 9;
    int ksteps = K >> 5;
    int kstep = rest % ksteps, otile = rest / ksteps;
    int o = otile * 16 + (lane & 15);
    int k = kstep * 32 + (lane >> 4) * 8 + e;
    float v;
    if (mode == 1)      v = W[(size_t)o * K + (k & 31) * 27 + (k >> 5)];
    else if (mode == 2) v = (o < 3) ? W[(size_t)o * K + k] : 0.f;
    else                v = W[(size_t)o * K + k];
    wf[n] = __float2bfloat16(v);
}

__global__ void k_prepw_all(const float* __restrict__ conv_w, const float* __restrict__ lfc_w,
                            const float* __restrict__ fc2_w, const float* __restrict__ fc3_w,
                            const float* __restrict__ fc4_w,
                            __hip_bfloat16* __restrict__ w0f, __hip_bfloat16* __restrict__ w1f,
                            __hip_bfloat16* __restrict__ w2f, __hip_bfloat16* __restrict__ w3f,
                            __hip_bfloat16* __restrict__ w4f) {
    int n = blockIdx.x * blockDim.x + threadIdx.x;
    if (n < 55296)                prep_one(conv_w, w0f, 864, 1, n);
    else if (n < 63488)           prep_one(lfc_w,  w1f, 64,  0, n - 55296);
    else if (n < 194560)          prep_one(fc2_w,  w2f, 256, 0, n - 63488);
    else if (n < 325632)          prep_one(fc3_w,  w3f, 512, 0, n - 194560);
    else if (n < 329728)          prep_one(fc4_w,  w4f, 256, 2, n - 325632);
}

// ================= spatial sort (counting sort by Morton cell) =================
__device__ __forceinline__ int point_cell(float px, float py, float pz) {
    int cx = min(63, max(0, (int)(px * 31.5f + 31.5f))) >> 3;
    int cy = min(63, max(0, (int)(py * 31.5f + 31.5f))) >> 3;
    int cz = min(63, max(0, (int)(pz * 31.5f + 31.5f))) >> 3;
    int k = 0;
#pragma unroll
    for (int b = 0; b < 3; ++b)
        k |= (((cx >> b) & 1) << (3 * b)) | (((cy >> b) & 1) << (3 * b + 1))
           | (((cz >> b) & 1) << (3 * b + 2));
    return k;
}

__global__ void k_hist(const float* __restrict__ xin, int* __restrict__ hist, int m) {
    int p = blockIdx.x * blockDim.x + threadIdx.x;
    if (p >= m) return;
    atomicAdd(&hist[point_cell(xin[p * 3], xin[p * 3 + 1], xin[p * 3 + 2])], 1);
}

// single-wave exclusive scan of 512 cells
__global__ __launch_bounds__(64)
void k_scan(const int* __restrict__ hist, int* __restrict__ cursor) {
    const int t = threadIdx.x;   // 0..63
    int vals[8];
    int s = 0;
#pragma unroll
    for (int k = 0; k < 8; ++k) { vals[k] = hist[t * 8 + k]; s += vals[k]; }
    int pre = s;
#pragma unroll
    for (int off = 1; off < 64; off <<= 1) {
        int u = __shfl_up(pre, off);
        if (t >= off) pre += u;
    }
    int run = pre - s;   // exclusive prefix of this lane's first cell
#pragma unroll
    for (int k = 0; k < 8; ++k) { cursor[t * 8 + k] = run; run += vals[k]; }
}

__global__ void k_scatter(const float* __restrict__ xin, int* __restrict__ cursor,
                          int* __restrict__ perm, int m) {
    int p = blockIdx.x * blockDim.x + threadIdx.x;
    if (p >= m) return;
    int cell = point_cell(xin[p * 3], xin[p * 3 + 1], xin[p * 3 + 2]);
    int pos = atomicAdd(&cursor[cell], 1);
    perm[pos] = p;
}

// ============ standalone sampler: 1 point/wave, 4 waves/block (r15, proven) ============
// zoS/zdS/wzS wave-uniform -> SGPR via readfirstlane (VGPR 56->36, fits (256,6));
// r15 measured: occupancy 68%, VALUBusy 88%, 161 us, no spill.
template <bool VT16, bool SORT>
__global__ __launch_bounds__(256, 6)
void k_sample(const float* __restrict__ xin, const void* __restrict__ vtp,
              const int* __restrict__ perm,
              __hip_bfloat16* __restrict__ fbuf, int m, int nblk) {
    __shared__ __align__(16) __hip_bfloat16 rowbuf[4][896];  // 864 + pad

    // bijective XCD swizzle: contiguous chunk of sorted points per XCD
    int b = blockIdx.x;
    {
        const int qd = nblk >> 3, r = nblk & 7;
        const int xcd = b & 7, i = b >> 3;
        b = (xcd < r) ? xcd * (qd + 1) + i : r * (qd + 1) + (xcd - r) * qd + i;
    }
    const int lane = threadIdx.x & 63;
    const int wv   = threadIdx.x >> 6;
    const int sp = b * 4 + wv;
    if (sp >= m) return;
    const int p = SORT ? perm[sp] : sp;

    const float px = xin[p * 3 + 0];
    const float py = xin[p * 3 + 1];
    const float pz = xin[p * 3 + 2];

    const int pr  = lane & 15;         // channel pair
    const int cxb = (lane >> 4) & 1;   // x corner
    const int cyb = (lane >> 5) & 1;   // y corner

    const float pxs = px * 31.5f + 31.5f;
    const float pys = py * 31.5f + 31.5f;
    const float pzs = pz * 31.5f + 31.5f;

    const int XS  = VT16 ? 6 : 7;
    const int YS  = VT16 ? 12 : 13;
    const int ZS  = VT16 ? 18 : 19;
    const int QS  = VT16 ? 24 : 25;
    const int PRB = VT16 ? 4 : 8;      // bytes per channel pair

    int   xoS[4][3], yoS[4][3], zoS[4][3], zdS[4][3];
    float wxS[4][3], wyS[4][3], wzS[4][3];
#pragma unroll
    for (int q = 0; q < 4; ++q) {
        const float sc31 = (float)(2 << q) * (31.5f / 64.0f);
#pragma unroll
        for (int pos = 0; pos < 3; ++pos) {
            const float gv = (-2.0f + 1.5f * (float)pos) * sc31;  // compile-time
            {   // x axis: per-lane (corner bit4, channel pr)
                float ix = fminf(fmaxf(pxs + gv, 0.f), 63.f);
                float xf = floorf(ix); int x0 = (int)xf; float fx = ix - xf;
                int x1 = min(x0 + 1, 63);
                xoS[q][pos] = ((cxb ? x1 : x0) << XS) + pr * PRB;
                wxS[q][pos] = cxb ? fx : 1.f - fx;
            }
            {   // y axis: per-lane (corner bit5)
                float iy = fminf(fmaxf(pys + gv, 0.f), 63.f);
                float yf = floorf(iy); int y0 = (int)yf; float fy = iy - yf;
                int y1 = min(y0 + 1, 63);
                yoS[q][pos] = (cyb ? y1 : y0) << YS;
                wyS[q][pos] = cyb ? fy : 1.f - fy;
            }
            {   // z axis: WAVE-UNIFORM -> SGPR via readfirstlane (frees ~36 VGPR)
                float iz = fminf(fmaxf(pzs + gv, 0.f), 63.f);
                float zf = floorf(iz); int z0 = (int)zf; float fz = iz - zf;
                int z1 = min(z0 + 1, 63);
                zoS[q][pos] = __builtin_amdgcn_readfirstlane((z0 << ZS) + (q << QS));
                zdS[q][pos] = __builtin_amdgcn_readfirstlane((z1 - z0) << ZS);
                wzS[q][pos] = __uint_as_float(
                    __builtin_amdgcn_readfirstlane(__float_as_uint(fz)));
            }
        }
    }

    // SRSRC for vt (wave-uniform base; per-lane 32-bit voffset)
    int32x4 srsrc;
    srsrc.x = (int)(unsigned)(uintptr_t)vtp;
    srsrc.y = (int)((uintptr_t)vtp >> 32);
    srsrc.z = -1;                            // bounds check off
    srsrc.w = 0x00020000;                    // raw dword access

    const char* __restrict__ vtb = (const char*)vtp;
#pragma unroll
    for (int j = 0; j < 3; ++j)
#pragma unroll
    for (int i = 0; i < 3; ++i) {
        int   yxo[4];
        float wyx[4];
#pragma unroll
        for (int q = 0; q < 4; ++q) {
            yxo[q] = yoS[q][i] + xoS[q][j];
            wyx[q] = wyS[q][i] * wxS[q][j];
        }
#pragma unroll
        for (int k = 0; k < 3; ++k) {
            f32x2 acc = {0.f, 0.f};
#pragma unroll
            for (int q = 0; q < 4; ++q) {
                const int a0 = zoS[q][k] + yxo[q];
                const int a1 = a0 + zdS[q][k];
                f32x2 r0, r1;
                if (VT16) {
                    const unsigned u0 = llvm_amdgcn_raw_buffer_load_u32(srsrc, a0, 0, 0);
                    const unsigned u1 = llvm_amdgcn_raw_buffer_load_u32(srsrc, a1, 0, 0);
                    r0.x = __uint_as_float(u0 << 16);
                    r0.y = __uint_as_float(u0 & 0xffff0000u);
                    r1.x = __uint_as_float(u1 << 16);
                    r1.y = __uint_as_float(u1 & 0xffff0000u);
                } else {
                    r0 = *(const f32x2*)(vtb + a0);
                    r1 = *(const f32x2*)(vtb + a1);
                }
                const float fz = wzS[q][k];
                const f32x2 fz2  = {fz, fz};
                const f32x2 wyx2 = {wyx[q], wyx[q]};
                const f32x2 t = r0 + (r1 - r0) * fz2;   // z-lerp
                acc = acc + t * wyx2;
            }
            float ax = acc.x, ay = acc.y;
            ax += __shfl_xor(ax, 16); ax += __shfl_xor(ax, 32);
            ay += __shfl_xor(ay, 16); ay += __shfl_xor(ay, 32);
            if (lane < 16) {
                unsigned u;
                asm("v_cvt_pk_bf16_f32 %0, %1, %2" : "=v"(u) : "v"(ax), "v"(ay));
                ((unsigned*)&rowbuf[wv][0])[(j * 9 + i * 3 + k) * 16 + pr] = u;
            }
        }
    }

    // dense row write, NON-TEMPORAL (r7: fixed 10x write-amp + L2 thrash)
    {
        const f32x4* __restrict__ lsrc = (const f32x4*)&rowbuf[wv][0];
        f32x4* __restrict__ gdst = (f32x4*)(fbuf + (size_t)sp * 864);
#pragma unroll
        for (int r = 0; r < 2; ++r) {
            const int idx = r * 64 + lane;
            if (idx < 108) __builtin_nontemporal_store(lsrc[idx], &gdst[idx]);
        }
    }
}

// ============ MLP kernel v5: 32 pts/block, 512 thr, 8 waves; LDS 49 KB ============
// r16: time-multiplexed LDS unions — zcat∪z2l (zcat dead after fc2's reads;
// fc2 = compute / barrier / write) and z0l∪z3l (z0l dead after lfc). rowA
// staging dropped (conv reads A from L2-resident fbuf, ~10 us aggregate).
// 49 KB <= 53.3 KB -> 3 blocks/CU (6 waves/SIMD, +50% latency hiding) IF
// VGPR <= 84; (512,4) bounds kept so worst case is status-quo 2 blocks
// (r12-r14 lesson: never request more waves than the live-set fits).
template <bool SORT>
__global__ __launch_bounds__(512, 4)
void k_mlp(const float* __restrict__ xin, const __hip_bfloat16* __restrict__ fbuf,
           const int* __restrict__ perm,
           const __hip_bfloat16* __restrict__ w0f, const float* __restrict__ b0,
           const __hip_bfloat16* __restrict__ w1f, const float* __restrict__ b1,
           const float* __restrict__ fc1w, const float* __restrict__ fc1b,
           const __hip_bfloat16* __restrict__ w2f, const float* __restrict__ b2,
           const __hip_bfloat16* __restrict__ w3f, const float* __restrict__ b3,
           const __hip_bfloat16* __restrict__ w4f, const float* __restrict__ fc4b,
           float* __restrict__ out, int m) {
    __shared__ __align__(16) char shrA[32 * Z2_PAD * 2];   // 33.3 KB: zcat ∪ z2l
    __shared__ __align__(16) char shrB[32 * Z3_PAD * 2];   // 16.9 KB: z0l ∪ z3l
    __hip_bfloat16 (*zcat)[ZC_PAD] = (__hip_bfloat16(*)[ZC_PAD])shrA;  // fc1..fc2-read
    __hip_bfloat16 (*z2l)[Z2_PAD]  = (__hip_bfloat16(*)[Z2_PAD])shrA;  // fc2-write..fc3
    __hip_bfloat16 (*z0l)[Z0_PAD]  = (__hip_bfloat16(*)[Z0_PAD])shrB;  // conv..lfc
    __hip_bfloat16 (*z3l)[Z3_PAD]  = (__hip_bfloat16(*)[Z3_PAD])shrB;  // fc3..fc4

    const int tid  = threadIdx.x;
    const int wave = tid >> 6;     // 0..7
    const int lane = tid & 63;
    const int p0   = blockIdx.x * 32;
    const int row  = lane & 15, g = lane >> 4;

    // ---- fc1: z_point -> zcat[:,0:128] ----
    {
        const int ptp = tid >> 4;       // 0..31
        const int og  = tid & 15;
        const int sp  = min(p0 + ptp, m - 1);
        const int p   = SORT ? perm[sp] : sp;
        const float qx = xin[p * 3 + 0], qy = xin[p * 3 + 1], qz = xin[p * 3 + 2];
#pragma unroll
        for (int r = 0; r < 8; ++r) {
            const int o = og * 8 + r;
            float v = qx * fc1w[o * 3 + 0] + qy * fc1w[o * 3 + 1] + qz * fc1w[o * 3 + 2] + fc1b[o];
            v = fmaxf(v, 0.2f * v);
            zcat[ptp][o] = __float2bfloat16(v);
        }
    }

    // ---- conv [32x864]x[864x64]: wave = (wr:2 rows) x (wc:4 cols); A from fbuf ----
    {
        const int wc = wave & 3, wr = wave >> 2;
        const int sr = min(p0 + wr * 16 + row, m - 1);
        const __hip_bfloat16* arow = fbuf + (size_t)sr * 864;
        f32x4 acc = {0.f, 0.f, 0.f, 0.f};
#pragma unroll
        for (int ks = 0; ks < 27; ++ks) {
            short8 af = *(const short8*)(arow + ks * 32 + g * 8);
            short8 bf = *(const short8*)(w0f + (((size_t)wc * 27 + ks) * 64 + lane) * 8);
            acc = __builtin_amdgcn_mfma_f32_16x16x32_bf16(af, bf, acc, 0, 0, 0);
        }
        const int o = wc * 16 + row;
        const float bias = b0[o];
#pragma unroll
        for (int r = 0; r < 4; ++r)
            z0l[wr * 16 + g * 4 + r][o] = __float2bfloat16(acc[r] + bias);
    }
    __syncthreads();

    // ---- lfc [32x64]x[64x128]: tc = wave; B reused across 2 row-tiles ----
    {
        const int tc = wave;
        f32x4 acc0 = {0.f, 0.f, 0.f, 0.f}, acc1 = {0.f, 0.f, 0.f, 0.f};
#pragma unroll
        for (int ks = 0; ks < 2; ++ks) {
            short8 bf = *(const short8*)(w1f + (((size_t)tc * 2 + ks) * 64 + lane) * 8);
            short8 a0 = *(const short8*)&z0l[row][ks * 32 + g * 8];
            short8 a1 = *(const short8*)&z0l[16 + row][ks * 32 + g * 8];
            acc0 = __builtin_amdgcn_mfma_f32_16x16x32_bf16(a0, bf, acc0, 0, 0, 0);
            acc1 = __builtin_amdgcn_mfma_f32_16x16x32_bf16(a1, bf, acc1, 0, 0, 0);
        }
        const int o = tc * 16 + row;
        const float bias = b1[o];
#pragma unroll
        for (int r = 0; r < 4; ++r) {
            zcat[g * 4 + r][128 + o]      = __float2bfloat16(acc0[r] + bias);
            zcat[16 + g * 4 + r][128 + o] = __float2bfloat16(acc1[r] + bias);
        }
    }
    __syncthreads();

    // ---- fc2 [32x256]x[256x512]: compute (reads zcat) / barrier / write z2l ----
    {
        f32x4 acc[4][2];
#pragma unroll
        for (int c = 0; c < 4; ++c)
#pragma unroll
            for (int t = 0; t < 2; ++t) acc[c][t] = (f32x4){0.f, 0.f, 0.f, 0.f};
#pragma unroll
        for (int ks = 0; ks < 8; ++ks) {
            short8 a0 = *(const short8*)&zcat[row][ks * 32 + g * 8];
            short8 a1 = *(const short8*)&zcat[16 + row][ks * 32 + g * 8];
#pragma unroll
            for (int c = 0; c < 4; ++c) {
                short8 bf = *(const short8*)(w2f + (((size_t)(wave * 4 + c) * 8 + ks) * 64 + lane) * 8);
                acc[c][0] = __builtin_amdgcn_mfma_f32_16x16x32_bf16(a0, bf, acc[c][0], 0, 0, 0);
                acc[c][1] = __builtin_amdgcn_mfma_f32_16x16x32_bf16(a1, bf, acc[c][1], 0, 0, 0);
            }
        }
        __syncthreads();   // all zcat reads done before z2l overwrites the region
#pragma unroll
        for (int c = 0; c < 4; ++c) {
            const int o = (wave * 4 + c) * 16 + row;
            const float bias = b2[o];
#pragma unroll
            for (int r = 0; r < 4; ++r) {
                float v0 = acc[c][0][r] + bias; v0 = fmaxf(v0, 0.2f * v0);
                float v1 = acc[c][1][r] + bias; v1 = fmaxf(v1, 0.2f * v1);
                z2l[g * 4 + r][o]      = __float2bfloat16(v0);
                z2l[16 + g * 4 + r][o] = __float2bfloat16(v1);
            }
        }
    }
    __syncthreads();

    // ---- fc3 [32x512]x[512x256]: reads z2l (shrA), writes z3l (shrB; z0l dead) ----
    {
        f32x4 acc[2][2];
#pragma unroll
        for (int c = 0; c < 2; ++c)
#pragma unroll
            for (int t = 0; t < 2; ++t) acc[c][t] = (f32x4){0.f, 0.f, 0.f, 0.f};
#pragma unroll
        for (int ks = 0; ks < 16; ++ks) {
            short8 a0 = *(const short8*)&z2l[row][ks * 32 + g * 8];
            short8 a1 = *(const short8*)&z2l[16 + row][ks * 32 + g * 8];
#pragma unroll
            for (int c = 0; c < 2; ++c) {
                short8 bf = *(const short8*)(w3f + (((size_t)(wave * 2 + c) * 16 + ks) * 64 + lane) * 8);
                acc[c][0] = __builtin_amdgcn_mfma_f32_16x16x32_bf16(a0, bf, acc[c][0], 0, 0, 0);
                acc[c][1] = __builtin_amdgcn_mfma_f32_16x16x32_bf16(a1, bf, acc[c][1], 0, 0, 0);
            }
        }
#pragma unroll
        for (int c = 0; c < 2; ++c) {
            const int o = (wave * 2 + c) * 16 + row;
            const float bias = b3[o];
#pragma unroll
            for (int r = 0; r < 4; ++r) {
                float v0 = acc[c][0][r] + bias; v0 = fmaxf(v0, 0.2f * v0);
                float v1 = acc[c][1][r] + bias; v1 = fmaxf(v1, 0.2f * v1);
                z3l[g * 4 + r][o]      = __float2bfloat16(v0);
                z3l[16 + g * 4 + r][o] = __float2bfloat16(v1);
            }
        }
    }
    __syncthreads();

    // ---- fc4 [32x256]x[256x16(pad)]: waves 0..1 (tr = wave), 8 MFMA each ----
    if (wave < 2) {
        f32x4 acc = {0.f, 0.f, 0.f, 0.f};
#pragma unroll
        for (int ks = 0; ks < 8; ++ks) {
            short8 af = *(const short8*)&z3l[wave * 16 + row][ks * 32 + g * 8];
            short8 bf = *(const short8*)(w4f + (((size_t)ks) * 64 + lane) * 8);
            acc = __builtin_amdgcn_mfma_f32_16x16x32_bf16(af, bf, acc, 0, 0, 0);
        }
        const int o = row;
        if (o < 3) {
            const float bias = fc4b[o];
#pragma unroll
            for (int r = 0; r < 4; ++r) {
                const int spg = p0 + wave * 16 + g * 4 + r;
                if (spg < m) {
                    const int pg = SORT ? perm[spg] : spg;
                    out[pg * 3 + o] = acc[r] + bias;
                }
            }
        }
    }
}

extern "C" void kernel_launch(void* const* d_in, const int* in_sizes, int n_in,
                              void* d_out, int out_size, void* d_ws, size_t ws_size,
                              hipStream_t stream) {
    const float* x      = (const float*)d_in[1];
    const float* v0     = (const float*)d_in[2];
    const float* v1     = (const float*)d_in[3];
    const float* v2     = (const float*)d_in[4];
    const float* v3     = (const float*)d_in[5];
    const float* conv_w = (const float*)d_in[6];
    const float* conv_b = (const float*)d_in[7];
    const float* lfc_w  = (const float*)d_in[8];
    const float* lfc_b  = (const float*)d_in[9];
    const float* fc1_w  = (const float*)d_in[10];
    const float* fc1_b  = (const float*)d_in[11];
    const float* fc2_w  = (const float*)d_in[12];
    const float* fc2_b  = (const float*)d_in[13];
    const float* fc3_w  = (const float*)d_in[14];
    const float* fc3_b  = (const float*)d_in[15];
    const float* fc4_w  = (const float*)d_in[16];
    const float* fc4_b  = (const float*)d_in[17];
    float* out = (float*)d_out;
    const int m = in_sizes[1] / 3;

    char* ws = (char*)d_ws;
    size_t woff = 0;
    __hip_bfloat16* w0f = (__hip_bfloat16*)(ws + woff); woff += (size_t)55296 * 2;
    __hip_bfloat16* w1f = (__hip_bfloat16*)(ws + woff); woff += (size_t)8192 * 2;
    __hip_bfloat16* w2f = (__hip_bfloat16*)(ws + woff); woff += (size_t)131072 * 2;
    __hip_bfloat16* w3f = (__hip_bfloat16*)(ws + woff); woff += (size_t)131072 * 2;
    __hip_bfloat16* w4f = (__hip_bfloat16*)(ws + woff); woff += (size_t)4096 * 2;
    woff = (woff + 255) & ~(size_t)255;
    int* hist   = (int*)(ws + woff); woff += NCELL * 4;
    int* cursor = (int*)(ws + woff); woff += NCELL * 4;
    int* perm   = (int*)(ws + woff); woff += ((size_t)m * 4 + 255) & ~(size_t)255;

    const size_t vt32_bytes = (size_t)4 * VOXELS * 32 * 4;   // 128 MiB
    const size_t vt16_bytes = (size_t)4 * VOXELS * 32 * 2;   // 64 MiB
    const size_t fbytes     = ((size_t)m * 864 * 2 + 255) & ~(size_t)255;

    const size_t need_split16 = woff + vt16_bytes + fbytes;
    const size_t need_split32 = woff + vt32_bytes + fbytes;

    k_prepw_all<<<(329728 + 255) / 256, 256, 0, stream>>>(conv_w, lfc_w, fc2_w, fc3_w, fc4_w,
                                                          w0f, w1f, w2f, w3f, w4f);

    const int nsb = (m + 3) / 4;
    const int nb  = (m + 31) / 32;
    const int npb = (m + 255) / 256;

    if (ws_size >= need_split16) {
        // ---- preferred: bf16 channel-last vt + Morton sort ----
        void* vt = (void*)(ws + woff);
        __hip_bfloat16* fbuf = (__hip_bfloat16*)(ws + woff + vt16_bytes);
        hipMemsetAsync(hist, 0, NCELL * 4, stream);
        k_hist<<<npb, 256, 0, stream>>>(x, hist, m);
        k_scan<<<1, 64, 0, stream>>>(hist, cursor);
        k_scatter<<<npb, 256, 0, stream>>>(x, cursor, perm, m);
        k_transpose<true><<<16384, 256, 0, stream>>>(v0, v1, v2, v3, vt);
        k_sample<true, true><<<nsb, 256, 0, stream>>>(x, vt, perm, fbuf, m, nsb);
        k_mlp<true><<<nb, 512, 0, stream>>>(x, fbuf, perm, w0f, conv_b, w1f, lfc_b,
                                            fc1_w, fc1_b, w2f, fc2_b, w3f, fc3_b,
                                            w4f, fc4_b, out, m);
    } else if (ws_size >= need_split32) {
        void* vt = (void*)(ws + woff);
        __hip_bfloat16* fbuf = (__hip_bfloat16*)(ws + woff + vt32_bytes);
        hipMemsetAsync(hist, 0, NCELL * 4, stream);
        k_hist<<<npb, 256, 0, stream>>>(x, hist, m);
        k_scan<<<1, 64, 0, stream>>>(hist, cursor);
        k_scatter<<<npb, 256, 0, stream>>>(x, cursor, perm, m);
        k_transpose<false><<<16384, 256, 0, stream>>>(v0, v1, v2, v3, vt);
        k_sample<false, true><<<nsb, 256, 0, stream>>>(x, vt, perm, fbuf, m, nsb);
        k_mlp<true><<<nb, 512, 0, stream>>>(x, fbuf, perm, w0f, conv_b, w1f, lfc_b,
                                            fc1_w, fc1_b, w2f, fc2_b, w3f, fc3_b,
                                            w4f, fc4_b, out, m);
    } else {
        __hip_bfloat16* fbuf = (__hip_bfloat16*)(ws + woff);
        k_sample<false, false><<<nsb, 256, 0, stream>>>(x, nullptr, perm, fbuf, m, nsb);
        k_mlp<false><<<nb, 512, 0, stream>>>(x, fbuf, perm, w0f, conv_b, w1f, lfc_b,
                                             fc1_w, fc1_b, w2f, fc2_b, w3f, fc3_b,
                                             w4f, fc4_b, out, m);
    }
}

// Round 17
// 405.595 us; speedup vs baseline: 1.0471x; 1.0471x over previous
//
#include <hip/hip_runtime.h>
#include <hip/hip_bf16.h>

typedef __attribute__((ext_vector_type(8))) short short8;
typedef __attribute__((ext_vector_type(4))) float f32x4;
typedef __attribute__((ext_vector_type(2))) float f32x2;
typedef __attribute__((ext_vector_type(4))) int int32x4;

// raw buffer load: 32-bit voffset addressing (no per-lane 64-bit addr VALU).
__device__ unsigned int llvm_amdgcn_raw_buffer_load_u32(int32x4 srsrc, int voffset,
                                                        int soffset, int aux)
    __asm("llvm.amdgcn.raw.buffer.load.i32");

#define VOXELS 262144  // 64^3
#define ZC_PAD 264
#define Z0_PAD 72
#define Z2_PAD 520
#define Z3_PAD 264
#define NCELL  512     // 8x8x8 Morton cells

// ---------------- volume transpose: (C,D,H,W) -> (D,H,W,C) ----------------
template <bool VT16>
__global__ void k_transpose(const float* __restrict__ v0, const float* __restrict__ v1,
                            const float* __restrict__ v2, const float* __restrict__ v3,
                            void* __restrict__ vtp) {
    int b  = blockIdx.x;
    int q  = b >> 12;
    int zy = b & 4095;
    const float* src = (q == 0) ? v0 : (q == 1) ? v1 : (q == 2) ? v2 : v3;
    __shared__ float buf[32][65];
    int t = threadIdx.x;
    int x = t & 63, c0 = t >> 6;
    for (int cp = 0; cp < 32; cp += 4) {
        int c = c0 + cp;
        buf[c][x] = src[(size_t)c * VOXELS + (size_t)zy * 64 + x];
    }
    __syncthreads();
    const size_t base = ((size_t)q * VOXELS + (size_t)zy * 64) * 32;
    if (VT16) {
        // dword stores (2 bf16 channels/thread) -> 256 B contiguous per wave instr
        const int cp2 = t & 15;       // channel pair
        const int xg  = t >> 4;       // 16 x-positions per pass
        unsigned* dstw = (unsigned*)((__hip_bfloat16*)vtp + base);
        for (int xx = xg; xx < 64; xx += 16) {
            __hip_bfloat16 h0 = __float2bfloat16(buf[cp2 * 2][xx]);
            __hip_bfloat16 h1 = __float2bfloat16(buf[cp2 * 2 + 1][xx]);
            unsigned u = ((unsigned)*(unsigned short*)&h1 << 16) | *(unsigned short*)&h0;
            dstw[xx * 16 + cp2] = u;
        }
    } else {
        int c = t & 31, xg = t >> 5;
        for (int xx = xg; xx < 64; xx += 8) {
            ((float*)vtp)[base + xx * 32 + c] = buf[c][xx];
        }
    }
}

// ------------- merged weight pack: all 5 weight tensors in ONE launch -------------
__device__ __forceinline__ void prep_one(const float* __restrict__ W,
                                         __hip_bfloat16* __restrict__ wf,
                                         int K, int mode, int n) {
    int e = n & 7, lane = (n >> 3) & 63;
    int rest = n >> 9;
    int ksteps = K >> 5;
    int kstep = rest % ksteps, otile = rest / ksteps;
    int o = otile * 16 + (lane & 15);
    int k = kstep * 32 + (lane >> 4) * 8 + e;
    float v;
    if (mode == 1)      v = W[(size_t)o * K + (k & 31) * 27 + (k >> 5)];
    else if (mode == 2) v = (o < 3) ? W[(size_t)o * K + k] : 0.f;
    else                v = W[(size_t)o * K + k];
    wf[n] = __float2bfloat16(v);
}

__global__ void k_prepw_all(const float* __restrict__ conv_w, const float* __restrict__ lfc_w,
                            const float* __restrict__ fc2_w, const float* __restrict__ fc3_w,
                            const float* __restrict__ fc4_w,
                            __hip_bfloat16* __restrict__ w0f, __hip_bfloat16* __restrict__ w1f,
                            __hip_bfloat16* __restrict__ w2f, __hip_bfloat16* __restrict__ w3f,
                            __hip_bfloat16* __restrict__ w4f) {
    int n = blockIdx.x * blockDim.x + threadIdx.x;
    if (n < 55296)                prep_one(conv_w, w0f, 864, 1, n);
    else if (n < 63488)           prep_one(lfc_w,  w1f, 64,  0, n - 55296);
    else if (n < 194560)          prep_one(fc2_w,  w2f, 256, 0, n - 63488);
    else if (n < 325632)          prep_one(fc3_w,  w3f, 512, 0, n - 194560);
    else if (n < 329728)          prep_one(fc4_w,  w4f, 256, 2, n - 325632);
}

// ================= spatial sort (counting sort by Morton cell) =================
__device__ __forceinline__ int point_cell(float px, float py, float pz) {
    int cx = min(63, max(0, (int)(px * 31.5f + 31.5f))) >> 3;
    int cy = min(63, max(0, (int)(py * 31.5f + 31.5f))) >> 3;
    int cz = min(63, max(0, (int)(pz * 31.5f + 31.5f))) >> 3;
    int k = 0;
#pragma unroll
    for (int b = 0; b < 3; ++b)
        k |= (((cx >> b) & 1) << (3 * b)) | (((cy >> b) & 1) << (3 * b + 1))
           | (((cz >> b) & 1) << (3 * b + 2));
    return k;
}

__global__ void k_hist(const float* __restrict__ xin, int* __restrict__ hist, int m) {
    int p = blockIdx.x * blockDim.x + threadIdx.x;
    if (p >= m) return;
    atomicAdd(&hist[point_cell(xin[p * 3], xin[p * 3 + 1], xin[p * 3 + 2])], 1);
}

// single-wave exclusive scan of 512 cells
__global__ __launch_bounds__(64)
void k_scan(const int* __restrict__ hist, int* __restrict__ cursor) {
    const int t = threadIdx.x;   // 0..63
    int vals[8];
    int s = 0;
#pragma unroll
    for (int k = 0; k < 8; ++k) { vals[k] = hist[t * 8 + k]; s += vals[k]; }
    int pre = s;
#pragma unroll
    for (int off = 1; off < 64; off <<= 1) {
        int u = __shfl_up(pre, off);
        if (t >= off) pre += u;
    }
    int run = pre - s;   // exclusive prefix of this lane's first cell
#pragma unroll
    for (int k = 0; k < 8; ++k) { cursor[t * 8 + k] = run; run += vals[k]; }
}

__global__ void k_scatter(const float* __restrict__ xin, int* __restrict__ cursor,
                          int* __restrict__ perm, int m) {
    int p = blockIdx.x * blockDim.x + threadIdx.x;
    if (p >= m) return;
    int cell = point_cell(xin[p * 3], xin[p * 3 + 1], xin[p * 3 + 2]);
    int pos = atomicAdd(&cursor[cell], 1);
    perm[pos] = p;
}

// ============ standalone sampler: 1 point/wave, 4 waves/block (r15, proven) ============
// zoS/zdS/wzS wave-uniform -> SGPR via readfirstlane (VGPR 56->36, fits (256,6));
// r15 measured: occupancy 68%, VALUBusy 88%, 161 us, no spill.
template <bool VT16, bool SORT>
__global__ __launch_bounds__(256, 6)
void k_sample(const float* __restrict__ xin, const void* __restrict__ vtp,
              const int* __restrict__ perm,
              __hip_bfloat16* __restrict__ fbuf, int m, int nblk) {
    __shared__ __align__(16) __hip_bfloat16 rowbuf[4][896];  // 864 + pad

    // bijective XCD swizzle: contiguous chunk of sorted points per XCD
    int b = blockIdx.x;
    {
        const int qd = nblk >> 3, r = nblk & 7;
        const int xcd = b & 7, i = b >> 3;
        b = (xcd < r) ? xcd * (qd + 1) + i : r * (qd + 1) + (xcd - r) * qd + i;
    }
    const int lane = threadIdx.x & 63;
    const int wv   = threadIdx.x >> 6;
    const int sp = b * 4 + wv;
    if (sp >= m) return;
    const int p = SORT ? perm[sp] : sp;

    const float px = xin[p * 3 + 0];
    const float py = xin[p * 3 + 1];
    const float pz = xin[p * 3 + 2];

    const int pr  = lane & 15;         // channel pair
    const int cxb = (lane >> 4) & 1;   // x corner
    const int cyb = (lane >> 5) & 1;   // y corner

    const float pxs = px * 31.5f + 31.5f;
    const float pys = py * 31.5f + 31.5f;
    const float pzs = pz * 31.5f + 31.5f;

    const int XS  = VT16 ? 6 : 7;
    const int YS  = VT16 ? 12 : 13;
    const int ZS  = VT16 ? 18 : 19;
    const int QS  = VT16 ? 24 : 25;
    const int PRB = VT16 ? 4 : 8;      // bytes per channel pair

    int   xoS[4][3], yoS[4][3], zoS[4][3], zdS[4][3];
    float wxS[4][3], wyS[4][3], wzS[4][3];
#pragma unroll
    for (int q = 0; q < 4; ++q) {
        const float sc31 = (float)(2 << q) * (31.5f / 64.0f);
#pragma unroll
        for (int pos = 0; pos < 3; ++pos) {
            const float gv = (-2.0f + 1.5f * (float)pos) * sc31;  // compile-time
            {   // x axis: per-lane (corner bit4, channel pr)
                float ix = fminf(fmaxf(pxs + gv, 0.f), 63.f);
                float xf = floorf(ix); int x0 = (int)xf; float fx = ix - xf;
                int x1 = min(x0 + 1, 63);
                xoS[q][pos] = ((cxb ? x1 : x0) << XS) + pr * PRB;
                wxS[q][pos] = cxb ? fx : 1.f - fx;
            }
            {   // y axis: per-lane (corner bit5)
                float iy = fminf(fmaxf(pys + gv, 0.f), 63.f);
                float yf = floorf(iy); int y0 = (int)yf; float fy = iy - yf;
                int y1 = min(y0 + 1, 63);
                yoS[q][pos] = (cyb ? y1 : y0) << YS;
                wyS[q][pos] = cyb ? fy : 1.f - fy;
            }
            {   // z axis: WAVE-UNIFORM -> SGPR via readfirstlane (frees ~36 VGPR)
                float iz = fminf(fmaxf(pzs + gv, 0.f), 63.f);
                float zf = floorf(iz); int z0 = (int)zf; float fz = iz - zf;
                int z1 = min(z0 + 1, 63);
                zoS[q][pos] = __builtin_amdgcn_readfirstlane((z0 << ZS) + (q << QS));
                zdS[q][pos] = __builtin_amdgcn_readfirstlane((z1 - z0) << ZS);
                wzS[q][pos] = __uint_as_float(
                    __builtin_amdgcn_readfirstlane(__float_as_uint(fz)));
            }
        }
    }

    // SRSRC for vt (wave-uniform base; per-lane 32-bit voffset)
    int32x4 srsrc;
    srsrc.x = (int)(unsigned)(uintptr_t)vtp;
    srsrc.y = (int)((uintptr_t)vtp >> 32);
    srsrc.z = -1;                            // bounds check off
    srsrc.w = 0x00020000;                    // raw dword access

    const char* __restrict__ vtb = (const char*)vtp;
#pragma unroll
    for (int j = 0; j < 3; ++j)
#pragma unroll
    for (int i = 0; i < 3; ++i) {
        int   yxo[4];
        float wyx[4];
#pragma unroll
        for (int q = 0; q < 4; ++q) {
            yxo[q] = yoS[q][i] + xoS[q][j];
            wyx[q] = wyS[q][i] * wxS[q][j];
        }
#pragma unroll
        for (int k = 0; k < 3; ++k) {
            f32x2 acc = {0.f, 0.f};
#pragma unroll
            for (int q = 0; q < 4; ++q) {
                const int a0 = zoS[q][k] + yxo[q];
                const int a1 = a0 + zdS[q][k];
                f32x2 r0, r1;
                if (VT16) {
                    const unsigned u0 = llvm_amdgcn_raw_buffer_load_u32(srsrc, a0, 0, 0);
                    const unsigned u1 = llvm_amdgcn_raw_buffer_load_u32(srsrc, a1, 0, 0);
                    r0.x = __uint_as_float(u0 << 16);
                    r0.y = __uint_as_float(u0 & 0xffff0000u);
                    r1.x = __uint_as_float(u1 << 16);
                    r1.y = __uint_as_float(u1 & 0xffff0000u);
                } else {
                    r0 = *(const f32x2*)(vtb + a0);
                    r1 = *(const f32x2*)(vtb + a1);
                }
                const float fz = wzS[q][k];
                const f32x2 fz2  = {fz, fz};
                const f32x2 wyx2 = {wyx[q], wyx[q]};
                const f32x2 t = r0 + (r1 - r0) * fz2;   // z-lerp
                acc = acc + t * wyx2;
            }
            float ax = acc.x, ay = acc.y;
            ax += __shfl_xor(ax, 16); ax += __shfl_xor(ax, 32);
            ay += __shfl_xor(ay, 16); ay += __shfl_xor(ay, 32);
            if (lane < 16) {
                unsigned u;
                asm("v_cvt_pk_bf16_f32 %0, %1, %2" : "=v"(u) : "v"(ax), "v"(ay));
                ((unsigned*)&rowbuf[wv][0])[(j * 9 + i * 3 + k) * 16 + pr] = u;
            }
        }
    }

    // dense row write, NON-TEMPORAL (r7: fixed 10x write-amp + L2 thrash)
    {
        const f32x4* __restrict__ lsrc = (const f32x4*)&rowbuf[wv][0];
        f32x4* __restrict__ gdst = (f32x4*)(fbuf + (size_t)sp * 864);
#pragma unroll
        for (int r = 0; r < 2; ++r) {
            const int idx = r * 64 + lane;
            if (idx < 108) __builtin_nontemporal_store(lsrc[idx], &gdst[idx]);
        }
    }
}

// ============ MLP kernel (r11 staged version + cross-barrier B prefetch) ============
// r16 regressed: fbuf is NT-written (L2-bypass) so conv-from-fbuf re-read 4x
// from L3/HBM. Reverted to one-pass rowA LDS staging (r11). NEW: next phase's
// first B-fragments are loaded into registers BEFORE each barrier — loads stay
// in flight across the barrier, hiding the ~200cy L2 latency at phase restart.
template <bool SORT>
__global__ __launch_bounds__(512, 4)
void k_mlp(const float* __restrict__ xin, const __hip_bfloat16* __restrict__ fbuf,
           const int* __restrict__ perm,
           const __hip_bfloat16* __restrict__ w0f, const float* __restrict__ b0,
           const __hip_bfloat16* __restrict__ w1f, const float* __restrict__ b1,
           const float* __restrict__ fc1w, const float* __restrict__ fc1b,
           const __hip_bfloat16* __restrict__ w2f, const float* __restrict__ b2,
           const __hip_bfloat16* __restrict__ w3f, const float* __restrict__ b3,
           const __hip_bfloat16* __restrict__ w4f, const float* __restrict__ fc4b,
           float* __restrict__ out, int m) {
    __shared__ __align__(16) __hip_bfloat16 zcat[32][ZC_PAD];   // 16.9 KB
    __shared__ __align__(16) __hip_bfloat16 z0l[32][Z0_PAD];    //  4.6 KB
    __shared__ __align__(16) char shr[32 * 1744];               // 55.8 KB union
    __hip_bfloat16 (*rowA)[872]  = (__hip_bfloat16(*)[872])shr;            // stage+conv
    __hip_bfloat16 (*z2l)[Z2_PAD] = (__hip_bfloat16(*)[Z2_PAD])shr;        // fc2+
    __hip_bfloat16 (*z3l)[Z3_PAD] = (__hip_bfloat16(*)[Z3_PAD])(shr + 33280);

    const int tid  = threadIdx.x;
    const int wave = tid >> 6;     // 0..7
    const int lane = tid & 63;
    const int p0   = blockIdx.x * 32;
    const int row  = lane & 15, g = lane >> 4;

    // ---- stage 32 fbuf rows -> rowA (padded stride 872; 2-way bank alias) ----
    {
        const int rrow = (wave << 2) + (lane >> 4);   // 0..31
        const int srow = min(p0 + rrow, m - 1);
        const f32x4* __restrict__ src = (const f32x4*)(fbuf + (size_t)srow * 864);
        const int c16 = lane & 15;
#pragma unroll
        for (int k = 0; k < 7; ++k) {
            const int chunk = c16 + k * 16;
            if (chunk < 108)
                *(f32x4*)&rowA[rrow][chunk * 8] = src[chunk];
        }
    }

    // ---- fc1: z_point -> zcat[:,0:128] ----
    {
        const int ptp = tid >> 4;       // 0..31
        const int og  = tid & 15;
        const int sp  = min(p0 + ptp, m - 1);
        const int p   = SORT ? perm[sp] : sp;
        const float qx = xin[p * 3 + 0], qy = xin[p * 3 + 1], qz = xin[p * 3 + 2];
#pragma unroll
        for (int r = 0; r < 8; ++r) {
            const int o = og * 8 + r;
            float v = qx * fc1w[o * 3 + 0] + qy * fc1w[o * 3 + 1] + qz * fc1w[o * 3 + 2] + fc1b[o];
            v = fmaxf(v, 0.2f * v);
            zcat[ptp][o] = __float2bfloat16(v);
        }
    }
    __syncthreads();

    // ---- conv [32x864]x[864x64]: wave = (wr:2 rows) x (wc:4 cols); A from LDS ----
    {
        const int wc = wave & 3, wr = wave >> 2;
        f32x4 acc = {0.f, 0.f, 0.f, 0.f};
#pragma unroll
        for (int ks = 0; ks < 27; ++ks) {
            short8 af = *(const short8*)&rowA[wr * 16 + row][ks * 32 + g * 8];
            short8 bf = *(const short8*)(w0f + (((size_t)wc * 27 + ks) * 64 + lane) * 8);
            acc = __builtin_amdgcn_mfma_f32_16x16x32_bf16(af, bf, acc, 0, 0, 0);
        }
        const int o = wc * 16 + row;
        const float bias = b0[o];
#pragma unroll
        for (int r = 0; r < 4; ++r)
            z0l[wr * 16 + g * 4 + r][o] = __float2bfloat16(acc[r] + bias);
    }
    __syncthreads();

    // ---- lfc [32x64]x[64x128]: tc = wave; B reused across 2 row-tiles ----
    short8 pf2[4];   // prefetch: fc2's ks=0 B-fragments, issued before the barrier
    {
        const int tc = wave;
        f32x4 acc0 = {0.f, 0.f, 0.f, 0.f}, acc1 = {0.f, 0.f, 0.f, 0.f};
#pragma unroll
        for (int ks = 0; ks < 2; ++ks) {
            short8 bf = *(const short8*)(w1f + (((size_t)tc * 2 + ks) * 64 + lane) * 8);
            short8 a0 = *(const short8*)&z0l[row][ks * 32 + g * 8];
            short8 a1 = *(const short8*)&z0l[16 + row][ks * 32 + g * 8];
            acc0 = __builtin_amdgcn_mfma_f32_16x16x32_bf16(a0, bf, acc0, 0, 0, 0);
            acc1 = __builtin_amdgcn_mfma_f32_16x16x32_bf16(a1, bf, acc1, 0, 0, 0);
        }
#pragma unroll
        for (int c = 0; c < 4; ++c)
            pf2[c] = *(const short8*)(w2f + (((size_t)(wave * 4 + c) * 8) * 64 + lane) * 8);
        const int o = tc * 16 + row;
        const float bias = b1[o];
#pragma unroll
        for (int r = 0; r < 4; ++r) {
            zcat[g * 4 + r][128 + o]      = __float2bfloat16(acc0[r] + bias);
            zcat[16 + g * 4 + r][128 + o] = __float2bfloat16(acc1[r] + bias);
        }
    }
    __syncthreads();

    // ---- fc2 [32x256]x[256x512]: tc = wave*4+c; ks=0 B from prefetch ----
    short8 pf3[2];   // prefetch: fc3's ks=0 B-fragments
    {
        f32x4 acc[4][2];
#pragma unroll
        for (int c = 0; c < 4; ++c)
#pragma unroll
            for (int t = 0; t < 2; ++t) acc[c][t] = (f32x4){0.f, 0.f, 0.f, 0.f};
#pragma unroll
        for (int ks = 0; ks < 8; ++ks) {
            short8 a0 = *(const short8*)&zcat[row][ks * 32 + g * 8];
            short8 a1 = *(const short8*)&zcat[16 + row][ks * 32 + g * 8];
#pragma unroll
            for (int c = 0; c < 4; ++c) {
                short8 bf = (ks == 0) ? pf2[c]
                          : *(const short8*)(w2f + (((size_t)(wave * 4 + c) * 8 + ks) * 64 + lane) * 8);
                acc[c][0] = __builtin_amdgcn_mfma_f32_16x16x32_bf16(a0, bf, acc[c][0], 0, 0, 0);
                acc[c][1] = __builtin_amdgcn_mfma_f32_16x16x32_bf16(a1, bf, acc[c][1], 0, 0, 0);
            }
        }
#pragma unroll
        for (int c = 0; c < 2; ++c)
            pf3[c] = *(const short8*)(w3f + (((size_t)(wave * 2 + c) * 16) * 64 + lane) * 8);
#pragma unroll
        for (int c = 0; c < 4; ++c) {
            const int o = (wave * 4 + c) * 16 + row;
            const float bias = b2[o];
#pragma unroll
            for (int r = 0; r < 4; ++r) {
                float v0 = acc[c][0][r] + bias; v0 = fmaxf(v0, 0.2f * v0);
                float v1 = acc[c][1][r] + bias; v1 = fmaxf(v1, 0.2f * v1);
                z2l[g * 4 + r][o]      = __float2bfloat16(v0);
                z2l[16 + g * 4 + r][o] = __float2bfloat16(v1);
            }
        }
    }
    __syncthreads();

    // ---- fc3 [32x512]x[512x256]: tc = wave*2+c; ks=0 B from prefetch ----
    {
        f32x4 acc[2][2];
#pragma unroll
        for (int c = 0; c < 2; ++c)
#pragma unroll
            for (int t = 0; t < 2; ++t) acc[c][t] = (f32x4){0.f, 0.f, 0.f, 0.f};
#pragma unroll
        for (int ks = 0; ks < 16; ++ks) {
            short8 a0 = *(const short8*)&z2l[row][ks * 32 + g * 8];
            short8 a1 = *(const short8*)&z2l[16 + row][ks * 32 + g * 8];
#pragma unroll
            for (int c = 0; c < 2; ++c) {
                short8 bf = (ks == 0) ? pf3[c]
                          : *(const short8*)(w3f + (((size_t)(wave * 2 + c) * 16 + ks) * 64 + lane) * 8);
                acc[c][0] = __builtin_amdgcn_mfma_f32_16x16x32_bf16(a0, bf, acc[c][0], 0, 0, 0);
                acc[c][1] = __builtin_amdgcn_mfma_f32_16x16x32_bf16(a1, bf, acc[c][1], 0, 0, 0);
            }
        }
#pragma unroll
        for (int c = 0; c < 2; ++c) {
            const int o = (wave * 2 + c) * 16 + row;
            const float bias = b3[o];
#pragma unroll
            for (int r = 0; r < 4; ++r) {
                float v0 = acc[c][0][r] + bias; v0 = fmaxf(v0, 0.2f * v0);
                float v1 = acc[c][1][r] + bias; v1 = fmaxf(v1, 0.2f * v1);
                z3l[g * 4 + r][o]      = __float2bfloat16(v0);
                z3l[16 + g * 4 + r][o] = __float2bfloat16(v1);
            }
        }
    }
    __syncthreads();

    // ---- fc4 [32x256]x[256x16(pad)]: waves 0..1 (tr = wave), 8 MFMA each ----
    if (wave < 2) {
        f32x4 acc = {0.f, 0.f, 0.f, 0.f};
#pragma unroll
        for (int ks = 0; ks < 8; ++ks) {
            short8 af = *(const short8*)&z3l[wave * 16 + row][ks * 32 + g * 8];
            short8 bf = *(const short8*)(w4f + (((size_t)ks) * 64 + lane) * 8);
            acc = __builtin_amdgcn_mfma_f32_16x16x32_bf16(af, bf, acc, 0, 0, 0);
        }
        const int o = row;
        if (o < 3) {
            const float bias = fc4b[o];
#pragma unroll
            for (int r = 0; r < 4; ++r) {
                const int spg = p0 + wave * 16 + g * 4 + r;
                if (spg < m) {
                    const int pg = SORT ? perm[spg] : spg;
                    out[pg * 3 + o] = acc[r] + bias;
                }
            }
        }
    }
}

extern "C" void kernel_launch(void* const* d_in, const int* in_sizes, int n_in,
                              void* d_out, int out_size, void* d_ws, size_t ws_size,
                              hipStream_t stream) {
    const float* x      = (const float*)d_in[1];
    const float* v0     = (const float*)d_in[2];
    const float* v1     = (const float*)d_in[3];
    const float* v2     = (const float*)d_in[4];
    const float* v3     = (const float*)d_in[5];
    const float* conv_w = (const float*)d_in[6];
    const float* conv_b = (const float*)d_in[7];
    const float* lfc_w  = (const float*)d_in[8];
    const float* lfc_b  = (const float*)d_in[9];
    const float* fc1_w  = (const float*)d_in[10];
    const float* fc1_b  = (const float*)d_in[11];
    const float* fc2_w  = (const float*)d_in[12];
    const float* fc2_b  = (const float*)d_in[13];
    const float* fc3_w  = (const float*)d_in[14];
    const float* fc3_b  = (const float*)d_in[15];
    const float* fc4_w  = (const float*)d_in[16];
    const float* fc4_b  = (const float*)d_in[17];
    float* out = (float*)d_out;
    const int m = in_sizes[1] / 3;

    char* ws = (char*)d_ws;
    size_t woff = 0;
    __hip_bfloat16* w0f = (__hip_bfloat16*)(ws + woff); woff += (size_t)55296 * 2;
    __hip_bfloat16* w1f = (__hip_bfloat16*)(ws + woff); woff += (size_t)8192 * 2;
    __hip_bfloat16* w2f = (__hip_bfloat16*)(ws + woff); woff += (size_t)131072 * 2;
    __hip_bfloat16* w3f = (__hip_bfloat16*)(ws + woff); woff += (size_t)131072 * 2;
    __hip_bfloat16* w4f = (__hip_bfloat16*)(ws + woff); woff += (size_t)4096 * 2;
    woff = (woff + 255) & ~(size_t)255;
    int* hist   = (int*)(ws + woff); woff += NCELL * 4;
    int* cursor = (int*)(ws + woff); woff += NCELL * 4;
    int* perm   = (int*)(ws + woff); woff += ((size_t)m * 4 + 255) & ~(size_t)255;

    const size_t vt32_bytes = (size_t)4 * VOXELS * 32 * 4;   // 128 MiB
    const size_t vt16_bytes = (size_t)4 * VOXELS * 32 * 2;   // 64 MiB
    const size_t fbytes     = ((size_t)m * 864 * 2 + 255) & ~(size_t)255;

    const size_t need_split16 = woff + vt16_bytes + fbytes;
    const size_t need_split32 = woff + vt32_bytes + fbytes;

    k_prepw_all<<<(329728 + 255) / 256, 256, 0, stream>>>(conv_w, lfc_w, fc2_w, fc3_w, fc4_w,
                                                          w0f, w1f, w2f, w3f, w4f);

    const int nsb = (m + 3) / 4;
    const int nb  = (m + 31) / 32;
    const int npb = (m + 255) / 256;

    if (ws_size >= need_split16) {
        // ---- preferred: bf16 channel-last vt + Morton sort ----
        void* vt = (void*)(ws + woff);
        __hip_bfloat16* fbuf = (__hip_bfloat16*)(ws + woff + vt16_bytes);
        hipMemsetAsync(hist, 0, NCELL * 4, stream);
        k_hist<<<npb, 256, 0, stream>>>(x, hist, m);
        k_scan<<<1, 64, 0, stream>>>(hist, cursor);
        k_scatter<<<npb, 256, 0, stream>>>(x, cursor, perm, m);
        k_transpose<true><<<16384, 256, 0, stream>>>(v0, v1, v2, v3, vt);
        k_sample<true, true><<<nsb, 256, 0, stream>>>(x, vt, perm, fbuf, m, nsb);
        k_mlp<true><<<nb, 512, 0, stream>>>(x, fbuf, perm, w0f, conv_b, w1f, lfc_b,
                                            fc1_w, fc1_b, w2f, fc2_b, w3f, fc3_b,
                                            w4f, fc4_b, out, m);
    } else if (ws_size >= need_split32) {
        void* vt = (void*)(ws + woff);
        __hip_bfloat16* fbuf = (__hip_bfloat16*)(ws + woff + vt32_bytes);
        hipMemsetAsync(hist, 0, NCELL * 4, stream);
        k_hist<<<npb, 256, 0, stream>>>(x, hist, m);
        k_scan<<<1, 64, 0, stream>>>(hist, cursor);
        k_scatter<<<npb, 256, 0, stream>>>(x, cursor, perm, m);
        k_transpose<false><<<16384, 256, 0, stream>>>(v0, v1, v2, v3, vt);
        k_sample<false, true><<<nsb, 256, 0, stream>>>(x, vt, perm, fbuf, m, nsb);
        k_mlp<true><<<nb, 512, 0, stream>>>(x, fbuf, perm, w0f, conv_b, w1f, lfc_b,
                                            fc1_w, fc1_b, w2f, fc2_b, w3f, fc3_b,
                                            w4f, fc4_b, out, m);
    } else {
        __hip_bfloat16* fbuf = (__hip_bfloat16*)(ws + woff);
        k_sample<false, false><<<nsb, 256, 0, stream>>>(x, nullptr, perm, fbuf, m, nsb);
        k_mlp<false><<<nb, 512, 0, stream>>>(x, fbuf, perm, w0f, conv_b, w1f, lfc_b,
                                             fc1_w, fc1_b, w2f, fc2_b, w3f, fc3_b,
                                             w4f, fc4_b, out, m);
    }
}

// Round 18
// 399.512 us; speedup vs baseline: 1.0630x; 1.0152x over previous
//
#include <hip/hip_runtime.h>
#include <hip/hip_bf16.h>

typedef __attribute__((ext_vector_type(8))) short short8;
typedef __attribute__((ext_vector_type(4))) float f32x4;
typedef __attribute__((ext_vector_type(2))) float f32x2;
typedef __attribute__((ext_vector_type(4))) int int32x4;

// raw buffer load: 32-bit voffset addressing (no per-lane 64-bit addr VALU).
__device__ unsigned int llvm_amdgcn_raw_buffer_load_u32(int32x4 srsrc, int voffset,
                                                        int soffset, int aux)
    __asm("llvm.amdgcn.raw.buffer.load.i32");

#define VOXELS 262144  // 64^3
#define ZC_PAD 264
#define Z0_PAD 72
#define Z2_PAD 520
#define Z3_PAD 264
#define NCELL  512     // 8x8x8 Morton cells

#define NB_TR  16384   // transpose blocks
#define NB_PW  1288    // prepw blocks (329728/256)

// ================= spatial sort helpers =================
__device__ __forceinline__ int point_cell(float px, float py, float pz) {
    int cx = min(63, max(0, (int)(px * 31.5f + 31.5f))) >> 3;
    int cy = min(63, max(0, (int)(py * 31.5f + 31.5f))) >> 3;
    int cz = min(63, max(0, (int)(pz * 31.5f + 31.5f))) >> 3;
    int k = 0;
#pragma unroll
    for (int b = 0; b < 3; ++b)
        k |= (((cx >> b) & 1) << (3 * b)) | (((cy >> b) & 1) << (3 * b + 1))
           | (((cz >> b) & 1) << (3 * b + 2));
    return k;
}

__device__ __forceinline__ void prep_one(const float* __restrict__ W,
                                         __hip_bfloat16* __restrict__ wf,
                                         int K, int mode, int n) {
    int e = n & 7, lane = (n >> 3) & 63;
    int rest = n >> 9;
    int ksteps = K >> 5;
    int kstep = rest % ksteps, otile = rest / ksteps;
    int o = otile * 16 + (lane & 15);
    int k = kstep * 32 + (lane >> 4) * 8 + e;
    float v;
    if (mode == 1)      v = W[(size_t)o * K + (k & 31) * 27 + (k >> 5)];
    else if (mode == 2) v = (o < 3) ? W[(size_t)o * K + k] : 0.f;
    else                v = W[(size_t)o * K + k];
    wf[n] = __float2bfloat16(v);
}

// ======== merged front-end: transpose (bf16) + weight-pack + hist in ONE launch ========
// r18: these three are mutually independent; grid-partitioned so they run
// CONCURRENTLY (time ~= max ~42us instead of sum ~62us). hist is zeroed by a
// preceding hipMemsetAsync.
__global__ void k_front(const float* __restrict__ v0, const float* __restrict__ v1,
                        const float* __restrict__ v2, const float* __restrict__ v3,
                        __hip_bfloat16* __restrict__ vt,
                        const float* __restrict__ conv_w, const float* __restrict__ lfc_w,
                        const float* __restrict__ fc2_w, const float* __restrict__ fc3_w,
                        const float* __restrict__ fc4_w,
                        __hip_bfloat16* __restrict__ w0f, __hip_bfloat16* __restrict__ w1f,
                        __hip_bfloat16* __restrict__ w2f, __hip_bfloat16* __restrict__ w3f,
                        __hip_bfloat16* __restrict__ w4f,
                        const float* __restrict__ xin, int* __restrict__ hist, int m) {
    __shared__ float buf[32][65];
    const int blk = blockIdx.x;
    const int t   = threadIdx.x;

    if (blk < NB_TR) {
        // ---- volume transpose: (C,D,H,W) -> (D,H,W,C) bf16 ----
        const int q  = blk >> 12;
        const int zy = blk & 4095;
        const float* src = (q == 0) ? v0 : (q == 1) ? v1 : (q == 2) ? v2 : v3;
        const int x = t & 63, c0 = t >> 6;
        for (int cp = 0; cp < 32; cp += 4) {
            int c = c0 + cp;
            buf[c][x] = src[(size_t)c * VOXELS + (size_t)zy * 64 + x];
        }
        __syncthreads();
        const size_t base = ((size_t)q * VOXELS + (size_t)zy * 64) * 32;
        const int cp2 = t & 15;       // channel pair
        const int xg  = t >> 4;       // 16 x-positions per pass
        unsigned* dstw = (unsigned*)(vt + base);
        for (int xx = xg; xx < 64; xx += 16) {
            __hip_bfloat16 h0 = __float2bfloat16(buf[cp2 * 2][xx]);
            __hip_bfloat16 h1 = __float2bfloat16(buf[cp2 * 2 + 1][xx]);
            unsigned u = ((unsigned)*(unsigned short*)&h1 << 16) | *(unsigned short*)&h0;
            dstw[xx * 16 + cp2] = u;
        }
    } else if (blk < NB_TR + NB_PW) {
        // ---- weight pack (B-fragment order) ----
        int n = (blk - NB_TR) * 256 + t;
        if (n < 55296)                prep_one(conv_w, w0f, 864, 1, n);
        else if (n < 63488)           prep_one(lfc_w,  w1f, 64,  0, n - 55296);
        else if (n < 194560)          prep_one(fc2_w,  w2f, 256, 0, n - 63488);
        else if (n < 325632)          prep_one(fc3_w,  w3f, 512, 0, n - 194560);
        else if (n < 329728)          prep_one(fc4_w,  w4f, 256, 2, n - 325632);
    } else {
        // ---- Morton-cell histogram ----
        int p = (blk - NB_TR - NB_PW) * 256 + t;
        if (p < m)
            atomicAdd(&hist[point_cell(xin[p * 3], xin[p * 3 + 1], xin[p * 3 + 2])], 1);
    }
}

// fp32 transpose kept for the (never-taken in practice) fallback path
__global__ void k_transpose32(const float* __restrict__ v0, const float* __restrict__ v1,
                              const float* __restrict__ v2, const float* __restrict__ v3,
                              float* __restrict__ vtp) {
    int b  = blockIdx.x;
    int q  = b >> 12;
    int zy = b & 4095;
    const float* src = (q == 0) ? v0 : (q == 1) ? v1 : (q == 2) ? v2 : v3;
    __shared__ float buf[32][65];
    int t = threadIdx.x;
    int x = t & 63, c0 = t >> 6;
    for (int cp = 0; cp < 32; cp += 4) {
        int c = c0 + cp;
        buf[c][x] = src[(size_t)c * VOXELS + (size_t)zy * 64 + x];
    }
    __syncthreads();
    const size_t base = ((size_t)q * VOXELS + (size_t)zy * 64) * 32;
    int c = t & 31, xg = t >> 5;
    for (int xx = xg; xx < 64; xx += 8) {
        vtp[base + xx * 32 + c] = buf[c][xx];
    }
}

// single-wave exclusive scan of 512 cells
__global__ __launch_bounds__(64)
void k_scan(const int* __restrict__ hist, int* __restrict__ cursor) {
    const int t = threadIdx.x;   // 0..63
    int vals[8];
    int s = 0;
#pragma unroll
    for (int k = 0; k < 8; ++k) { vals[k] = hist[t * 8 + k]; s += vals[k]; }
    int pre = s;
#pragma unroll
    for (int off = 1; off < 64; off <<= 1) {
        int u = __shfl_up(pre, off);
        if (t >= off) pre += u;
    }
    int run = pre - s;   // exclusive prefix of this lane's first cell
#pragma unroll
    for (int k = 0; k < 8; ++k) { cursor[t * 8 + k] = run; run += vals[k]; }
}

__global__ void k_scatter(const float* __restrict__ xin, int* __restrict__ cursor,
                          int* __restrict__ perm, int m) {
    int p = blockIdx.x * blockDim.x + threadIdx.x;
    if (p >= m) return;
    int cell = point_cell(xin[p * 3], xin[p * 3 + 1], xin[p * 3 + 2]);
    int pos = atomicAdd(&cursor[cell], 1);
    perm[pos] = p;
}

// ============ standalone sampler: 1 point/wave, 4 waves/block (r15, proven) ============
// zoS/zdS/wzS wave-uniform -> SGPR via readfirstlane (VGPR 56->36, fits (256,6));
// r15/r17 measured: occupancy ~69%, VALUBusy ~90%, ~158 us, no spill.
template <bool VT16, bool SORT>
__global__ __launch_bounds__(256, 6)
void k_sample(const float* __restrict__ xin, const void* __restrict__ vtp,
              const int* __restrict__ perm,
              __hip_bfloat16* __restrict__ fbuf, int m, int nblk) {
    __shared__ __align__(16) __hip_bfloat16 rowbuf[4][896];  // 864 + pad

    // bijective XCD swizzle: contiguous chunk of sorted points per XCD
    int b = blockIdx.x;
    {
        const int qd = nblk >> 3, r = nblk & 7;
        const int xcd = b & 7, i = b >> 3;
        b = (xcd < r) ? xcd * (qd + 1) + i : r * (qd + 1) + (xcd - r) * qd + i;
    }
    const int lane = threadIdx.x & 63;
    const int wv   = threadIdx.x >> 6;
    const int sp = b * 4 + wv;
    if (sp >= m) return;
    const int p = SORT ? perm[sp] : sp;

    const float px = xin[p * 3 + 0];
    const float py = xin[p * 3 + 1];
    const float pz = xin[p * 3 + 2];

    const int pr  = lane & 15;         // channel pair
    const int cxb = (lane >> 4) & 1;   // x corner
    const int cyb = (lane >> 5) & 1;   // y corner

    const float pxs = px * 31.5f + 31.5f;
    const float pys = py * 31.5f + 31.5f;
    const float pzs = pz * 31.5f + 31.5f;

    const int XS  = VT16 ? 6 : 7;
    const int YS  = VT16 ? 12 : 13;
    const int ZS  = VT16 ? 18 : 19;
    const int QS  = VT16 ? 24 : 25;
    const int PRB = VT16 ? 4 : 8;      // bytes per channel pair

    int   xoS[4][3], yoS[4][3], zoS[4][3], zdS[4][3];
    float wxS[4][3], wyS[4][3], wzS[4][3];
#pragma unroll
    for (int q = 0; q < 4; ++q) {
        const float sc31 = (float)(2 << q) * (31.5f / 64.0f);
#pragma unroll
        for (int pos = 0; pos < 3; ++pos) {
            const float gv = (-2.0f + 1.5f * (float)pos) * sc31;  // compile-time
            {   // x axis: per-lane (corner bit4, channel pr)
                float ix = fminf(fmaxf(pxs + gv, 0.f), 63.f);
                float xf = floorf(ix); int x0 = (int)xf; float fx = ix - xf;
                int x1 = min(x0 + 1, 63);
                xoS[q][pos] = ((cxb ? x1 : x0) << XS) + pr * PRB;
                wxS[q][pos] = cxb ? fx : 1.f - fx;
            }
            {   // y axis: per-lane (corner bit5)
                float iy = fminf(fmaxf(pys + gv, 0.f), 63.f);
                float yf = floorf(iy); int y0 = (int)yf; float fy = iy - yf;
                int y1 = min(y0 + 1, 63);
                yoS[q][pos] = (cyb ? y1 : y0) << YS;
                wyS[q][pos] = cyb ? fy : 1.f - fy;
            }
            {   // z axis: WAVE-UNIFORM -> SGPR via readfirstlane (frees ~36 VGPR)
                float iz = fminf(fmaxf(pzs + gv, 0.f), 63.f);
                float zf = floorf(iz); int z0 = (int)zf; float fz = iz - zf;
                int z1 = min(z0 + 1, 63);
                zoS[q][pos] = __builtin_amdgcn_readfirstlane((z0 << ZS) + (q << QS));
                zdS[q][pos] = __builtin_amdgcn_readfirstlane((z1 - z0) << ZS);
                wzS[q][pos] = __uint_as_float(
                    __builtin_amdgcn_readfirstlane(__float_as_uint(fz)));
            }
        }
    }

    // SRSRC for vt (wave-uniform base; per-lane 32-bit voffset)
    int32x4 srsrc;
    srsrc.x = (int)(unsigned)(uintptr_t)vtp;
    srsrc.y = (int)((uintptr_t)vtp >> 32);
    srsrc.z = -1;                            // bounds check off
    srsrc.w = 0x00020000;                    // raw dword access

    const char* __restrict__ vtb = (const char*)vtp;
#pragma unroll
    for (int j = 0; j < 3; ++j)
#pragma unroll
    for (int i = 0; i < 3; ++i) {
        int   yxo[4];
        float wyx[4];
#pragma unroll
        for (int q = 0; q < 4; ++q) {
            yxo[q] = yoS[q][i] + xoS[q][j];
            wyx[q] = wyS[q][i] * wxS[q][j];
        }
#pragma unroll
        for (int k = 0; k < 3; ++k) {
            f32x2 acc = {0.f, 0.f};
#pragma unroll
            for (int q = 0; q < 4; ++q) {
                const int a0 = zoS[q][k] + yxo[q];
                const int a1 = a0 + zdS[q][k];
                f32x2 r0, r1;
                if (VT16) {
                    const unsigned u0 = llvm_amdgcn_raw_buffer_load_u32(srsrc, a0, 0, 0);
                    const unsigned u1 = llvm_amdgcn_raw_buffer_load_u32(srsrc, a1, 0, 0);
                    r0.x = __uint_as_float(u0 << 16);
                    r0.y = __uint_as_float(u0 & 0xffff0000u);
                    r1.x = __uint_as_float(u1 << 16);
                    r1.y = __uint_as_float(u1 & 0xffff0000u);
                } else {
                    r0 = *(const f32x2*)(vtb + a0);
                    r1 = *(const f32x2*)(vtb + a1);
                }
                const float fz = wzS[q][k];
                const f32x2 fz2  = {fz, fz};
                const f32x2 wyx2 = {wyx[q], wyx[q]};
                const f32x2 t = r0 + (r1 - r0) * fz2;   // z-lerp
                acc = acc + t * wyx2;
            }
            float ax = acc.x, ay = acc.y;
            ax += __shfl_xor(ax, 16); ax += __shfl_xor(ax, 32);
            ay += __shfl_xor(ay, 16); ay += __shfl_xor(ay, 32);
            if (lane < 16) {
                unsigned u;
                asm("v_cvt_pk_bf16_f32 %0, %1, %2" : "=v"(u) : "v"(ax), "v"(ay));
                ((unsigned*)&rowbuf[wv][0])[(j * 9 + i * 3 + k) * 16 + pr] = u;
            }
        }
    }

    // dense row write, NON-TEMPORAL (r7: fixed 10x write-amp + L2 thrash)
    {
        const f32x4* __restrict__ lsrc = (const f32x4*)&rowbuf[wv][0];
        f32x4* __restrict__ gdst = (f32x4*)(fbuf + (size_t)sp * 864);
#pragma unroll
        for (int r = 0; r < 2; ++r) {
            const int idx = r * 64 + lane;
            if (idx < 108) __builtin_nontemporal_store(lsrc[idx], &gdst[idx]);
        }
    }
}

// ============ MLP kernel (r11 staged + cross-barrier B prefetch; r17) ============
template <bool SORT>
__global__ __launch_bounds__(512, 4)
void k_mlp(const float* __restrict__ xin, const __hip_bfloat16* __restrict__ fbuf,
           const int* __restrict__ perm,
           const __hip_bfloat16* __restrict__ w0f, const float* __restrict__ b0,
           const __hip_bfloat16* __restrict__ w1f, const float* __restrict__ b1,
           const float* __restrict__ fc1w, const float* __restrict__ fc1b,
           const __hip_bfloat16* __restrict__ w2f, const float* __restrict__ b2,
           const __hip_bfloat16* __restrict__ w3f, const float* __restrict__ b3,
           const __hip_bfloat16* __restrict__ w4f, const float* __restrict__ fc4b,
           float* __restrict__ out, int m) {
    __shared__ __align__(16) __hip_bfloat16 zcat[32][ZC_PAD];   // 16.9 KB
    __shared__ __align__(16) __hip_bfloat16 z0l[32][Z0_PAD];    //  4.6 KB
    __shared__ __align__(16) char shr[32 * 1744];               // 55.8 KB union
    __hip_bfloat16 (*rowA)[872]  = (__hip_bfloat16(*)[872])shr;            // stage+conv
    __hip_bfloat16 (*z2l)[Z2_PAD] = (__hip_bfloat16(*)[Z2_PAD])shr;        // fc2+
    __hip_bfloat16 (*z3l)[Z3_PAD] = (__hip_bfloat16(*)[Z3_PAD])(shr + 33280);

    const int tid  = threadIdx.x;
    const int wave = tid >> 6;     // 0..7
    const int lane = tid & 63;
    const int p0   = blockIdx.x * 32;
    const int row  = lane & 15, g = lane >> 4;

    // ---- stage 32 fbuf rows -> rowA (padded stride 872; 2-way bank alias) ----
    {
        const int rrow = (wave << 2) + (lane >> 4);   // 0..31
        const int srow = min(p0 + rrow, m - 1);
        const f32x4* __restrict__ src = (const f32x4*)(fbuf + (size_t)srow * 864);
        const int c16 = lane & 15;
#pragma unroll
        for (int k = 0; k < 7; ++k) {
            const int chunk = c16 + k * 16;
            if (chunk < 108)
                *(f32x4*)&rowA[rrow][chunk * 8] = src[chunk];
        }
    }

    // ---- fc1: z_point -> zcat[:,0:128] ----
    {
        const int ptp = tid >> 4;       // 0..31
        const int og  = tid & 15;
        const int sp  = min(p0 + ptp, m - 1);
        const int p   = SORT ? perm[sp] : sp;
        const float qx = xin[p * 3 + 0], qy = xin[p * 3 + 1], qz = xin[p * 3 + 2];
#pragma unroll
        for (int r = 0; r < 8; ++r) {
            const int o = og * 8 + r;
            float v = qx * fc1w[o * 3 + 0] + qy * fc1w[o * 3 + 1] + qz * fc1w[o * 3 + 2] + fc1b[o];
            v = fmaxf(v, 0.2f * v);
            zcat[ptp][o] = __float2bfloat16(v);
        }
    }
    __syncthreads();

    // ---- conv [32x864]x[864x64]: wave = (wr:2 rows) x (wc:4 cols); A from LDS ----
    {
        const int wc = wave & 3, wr = wave >> 2;
        f32x4 acc = {0.f, 0.f, 0.f, 0.f};
#pragma unroll
        for (int ks = 0; ks < 27; ++ks) {
            short8 af = *(const short8*)&rowA[wr * 16 + row][ks * 32 + g * 8];
            short8 bf = *(const short8*)(w0f + (((size_t)wc * 27 + ks) * 64 + lane) * 8);
            acc = __builtin_amdgcn_mfma_f32_16x16x32_bf16(af, bf, acc, 0, 0, 0);
        }
        const int o = wc * 16 + row;
        const float bias = b0[o];
#pragma unroll
        for (int r = 0; r < 4; ++r)
            z0l[wr * 16 + g * 4 + r][o] = __float2bfloat16(acc[r] + bias);
    }
    __syncthreads();

    // ---- lfc [32x64]x[64x128]: tc = wave; B reused across 2 row-tiles ----
    short8 pf2[4];   // prefetch: fc2's ks=0 B-fragments, issued before the barrier
    {
        const int tc = wave;
        f32x4 acc0 = {0.f, 0.f, 0.f, 0.f}, acc1 = {0.f, 0.f, 0.f, 0.f};
#pragma unroll
        for (int ks = 0; ks < 2; ++ks) {
            short8 bf = *(const short8*)(w1f + (((size_t)tc * 2 + ks) * 64 + lane) * 8);
            short8 a0 = *(const short8*)&z0l[row][ks * 32 + g * 8];
            short8 a1 = *(const short8*)&z0l[16 + row][ks * 32 + g * 8];
            acc0 = __builtin_amdgcn_mfma_f32_16x16x32_bf16(a0, bf, acc0, 0, 0, 0);
            acc1 = __builtin_amdgcn_mfma_f32_16x16x32_bf16(a1, bf, acc1, 0, 0, 0);
        }
#pragma unroll
        for (int c = 0; c < 4; ++c)
            pf2[c] = *(const short8*)(w2f + (((size_t)(wave * 4 + c) * 8) * 64 + lane) * 8);
        const int o = tc * 16 + row;
        const float bias = b1[o];
#pragma unroll
        for (int r = 0; r < 4; ++r) {
            zcat[g * 4 + r][128 + o]      = __float2bfloat16(acc0[r] + bias);
            zcat[16 + g * 4 + r][128 + o] = __float2bfloat16(acc1[r] + bias);
        }
    }
    __syncthreads();

    // ---- fc2 [32x256]x[256x512]: tc = wave*4+c; ks=0 B from prefetch ----
    short8 pf3[2];   // prefetch: fc3's ks=0 B-fragments
    {
        f32x4 acc[4][2];
#pragma unroll
        for (int c = 0; c < 4; ++c)
#pragma unroll
            for (int t = 0; t < 2; ++t) acc[c][t] = (f32x4){0.f, 0.f, 0.f, 0.f};
#pragma unroll
        for (int ks = 0; ks < 8; ++ks) {
            short8 a0 = *(const short8*)&zcat[row][ks * 32 + g * 8];
            short8 a1 = *(const short8*)&zcat[16 + row][ks * 32 + g * 8];
#pragma unroll
            for (int c = 0; c < 4; ++c) {
                short8 bf = (ks == 0) ? pf2[c]
                          : *(const short8*)(w2f + (((size_t)(wave * 4 + c) * 8 + ks) * 64 + lane) * 8);
                acc[c][0] = __builtin_amdgcn_mfma_f32_16x16x32_bf16(a0, bf, acc[c][0], 0, 0, 0);
                acc[c][1] = __builtin_amdgcn_mfma_f32_16x16x32_bf16(a1, bf, acc[c][1], 0, 0, 0);
            }
        }
#pragma unroll
        for (int c = 0; c < 2; ++c)
            pf3[c] = *(const short8*)(w3f + (((size_t)(wave * 2 + c) * 16) * 64 + lane) * 8);
#pragma unroll
        for (int c = 0; c < 4; ++c) {
            const int o = (wave * 4 + c) * 16 + row;
            const float bias = b2[o];
#pragma unroll
            for (int r = 0; r < 4; ++r) {
                float v0 = acc[c][0][r] + bias; v0 = fmaxf(v0, 0.2f * v0);
                float v1 = acc[c][1][r] + bias; v1 = fmaxf(v1, 0.2f * v1);
                z2l[g * 4 + r][o]      = __float2bfloat16(v0);
                z2l[16 + g * 4 + r][o] = __float2bfloat16(v1);
            }
        }
    }
    __syncthreads();

    // ---- fc3 [32x512]x[512x256]: tc = wave*2+c; ks=0 B from prefetch ----
    {
        f32x4 acc[2][2];
#pragma unroll
        for (int c = 0; c < 2; ++c)
#pragma unroll
            for (int t = 0; t < 2; ++t) acc[c][t] = (f32x4){0.f, 0.f, 0.f, 0.f};
#pragma unroll
        for (int ks = 0; ks < 16; ++ks) {
            short8 a0 = *(const short8*)&z2l[row][ks * 32 + g * 8];
            short8 a1 = *(const short8*)&z2l[16 + row][ks * 32 + g * 8];
#pragma unroll
            for (int c = 0; c < 2; ++c) {
                short8 bf = (ks == 0) ? pf3[c]
                          : *(const short8*)(w3f + (((size_t)(wave * 2 + c) * 16 + ks) * 64 + lane) * 8);
                acc[c][0] = __builtin_amdgcn_mfma_f32_16x16x32_bf16(a0, bf, acc[c][0], 0, 0, 0);
                acc[c][1] = __builtin_amdgcn_mfma_f32_16x16x32_bf16(a1, bf, acc[c][1], 0, 0, 0);
            }
        }
#pragma unroll
        for (int c = 0; c < 2; ++c) {
            const int o = (wave * 2 + c) * 16 + row;
            const float bias = b3[o];
#pragma unroll
            for (int r = 0; r < 4; ++r) {
                float v0 = acc[c][0][r] + bias; v0 = fmaxf(v0, 0.2f * v0);
                float v1 = acc[c][1][r] + bias; v1 = fmaxf(v1, 0.2f * v1);
                z3l[g * 4 + r][o]      = __float2bfloat16(v0);
                z3l[16 + g * 4 + r][o] = __float2bfloat16(v1);
            }
        }
    }
    __syncthreads();

    // ---- fc4 [32x256]x[256x16(pad)]: waves 0..1 (tr = wave), 8 MFMA each ----
    if (wave < 2) {
        f32x4 acc = {0.f, 0.f, 0.f, 0.f};
#pragma unroll
        for (int ks = 0; ks < 8; ++ks) {
            short8 af = *(const short8*)&z3l[wave * 16 + row][ks * 32 + g * 8];
            short8 bf = *(const short8*)(w4f + (((size_t)ks) * 64 + lane) * 8);
            acc = __builtin_amdgcn_mfma_f32_16x16x32_bf16(af, bf, acc, 0, 0, 0);
        }
        const int o = row;
        if (o < 3) {
            const float bias = fc4b[o];
#pragma unroll
            for (int r = 0; r < 4; ++r) {
                const int spg = p0 + wave * 16 + g * 4 + r;
                if (spg < m) {
                    const int pg = SORT ? perm[spg] : spg;
                    out[pg * 3 + o] = acc[r] + bias;
                }
            }
        }
    }
}

extern "C" void kernel_launch(void* const* d_in, const int* in_sizes, int n_in,
                              void* d_out, int out_size, void* d_ws, size_t ws_size,
                              hipStream_t stream) {
    const float* x      = (const float*)d_in[1];
    const float* v0     = (const float*)d_in[2];
    const float* v1     = (const float*)d_in[3];
    const float* v2     = (const float*)d_in[4];
    const float* v3     = (const float*)d_in[5];
    const float* conv_w = (const float*)d_in[6];
    const float* conv_b = (const float*)d_in[7];
    const float* lfc_w  = (const float*)d_in[8];
    const float* lfc_b  = (const float*)d_in[9];
    const float* fc1_w  = (const float*)d_in[10];
    const float* fc1_b  = (const float*)d_in[11];
    const float* fc2_w  = (const float*)d_in[12];
    const float* fc2_b  = (const float*)d_in[13];
    const float* fc3_w  = (const float*)d_in[14];
    const float* fc3_b  = (const float*)d_in[15];
    const float* fc4_w  = (const float*)d_in[16];
    const float* fc4_b  = (const float*)d_in[17];
    float* out = (float*)d_out;
    const int m = in_sizes[1] / 3;

    char* ws = (char*)d_ws;
    size_t woff = 0;
    __hip_bfloat16* w0f = (__hip_bfloat16*)(ws + woff); woff += (size_t)55296 * 2;
    __hip_bfloat16* w1f = (__hip_bfloat16*)(ws + woff); woff += (size_t)8192 * 2;
    __hip_bfloat16* w2f = (__hip_bfloat16*)(ws + woff); woff += (size_t)131072 * 2;
    __hip_bfloat16* w3f = (__hip_bfloat16*)(ws + woff); woff += (size_t)131072 * 2;
    __hip_bfloat16* w4f = (__hip_bfloat16*)(ws + woff); woff += (size_t)4096 * 2;
    woff = (woff + 255) & ~(size_t)255;
    int* hist   = (int*)(ws + woff); woff += NCELL * 4;
    int* cursor = (int*)(ws + woff); woff += NCELL * 4;
    int* perm   = (int*)(ws + woff); woff += ((size_t)m * 4 + 255) & ~(size_t)255;

    const size_t vt32_bytes = (size_t)4 * VOXELS * 32 * 4;   // 128 MiB
    const size_t vt16_bytes = (size_t)4 * VOXELS * 32 * 2;   // 64 MiB
    const size_t fbytes     = ((size_t)m * 864 * 2 + 255) & ~(size_t)255;

    const size_t need_split16 = woff + vt16_bytes + fbytes;
    const size_t need_split32 = woff + vt32_bytes + fbytes;

    const int nsb = (m + 3) / 4;
    const int nb  = (m + 31) / 32;
    const int npb = (m + 255) / 256;

    if (ws_size >= need_split16) {
        // ---- preferred: bf16 channel-last vt + Morton sort; merged front-end ----
        __hip_bfloat16* vt = (__hip_bfloat16*)(ws + woff);
        __hip_bfloat16* fbuf = (__hip_bfloat16*)(ws + woff + vt16_bytes);
        hipMemsetAsync(hist, 0, NCELL * 4, stream);
        k_front<<<NB_TR + NB_PW + npb, 256, 0, stream>>>(
            v0, v1, v2, v3, vt, conv_w, lfc_w, fc2_w, fc3_w, fc4_w,
            w0f, w1f, w2f, w3f, w4f, x, hist, m);
        k_scan<<<1, 64, 0, stream>>>(hist, cursor);
        k_scatter<<<npb, 256, 0, stream>>>(x, cursor, perm, m);
        k_sample<true, true><<<nsb, 256, 0, stream>>>(x, vt, perm, fbuf, m, nsb);
        k_mlp<true><<<nb, 512, 0, stream>>>(x, fbuf, perm, w0f, conv_b, w1f, lfc_b,
                                            fc1_w, fc1_b, w2f, fc2_b, w3f, fc3_b,
                                            w4f, fc4_b, out, m);
    } else if (ws_size >= need_split32) {
        float* vt = (float*)(ws + woff);
        __hip_bfloat16* fbuf = (__hip_bfloat16*)(ws + woff + vt32_bytes);
        hipMemsetAsync(hist, 0, NCELL * 4, stream);
        // fallback: separate front-end kernels (fp32 vt)
        k_front<<<NB_TR + NB_PW + npb, 256, 0, stream>>>(        // prepw+hist still merged;
            v0, v1, v2, v3, (__hip_bfloat16*)vt /*unused bf16 vt*/, conv_w, lfc_w,
            fc2_w, fc3_w, fc4_w, w0f, w1f, w2f, w3f, w4f, x, hist, m);
        k_transpose32<<<16384, 256, 0, stream>>>(v0, v1, v2, v3, vt);
        k_scan<<<1, 64, 0, stream>>>(hist, cursor);
        k_scatter<<<npb, 256, 0, stream>>>(x, cursor, perm, m);
        k_sample<false, true><<<nsb, 256, 0, stream>>>(x, vt, perm, fbuf, m, nsb);
        k_mlp<true><<<nb, 512, 0, stream>>>(x, fbuf, perm, w0f, conv_b, w1f, lfc_b,
                                            fc1_w, fc1_b, w2f, fc2_b, w3f, fc3_b,
                                            w4f, fc4_b, out, m);
    } else {
        // minimal fallback (not expected: ws has been >=216 MB every round)
        __hip_bfloat16* fbuf = (__hip_bfloat16*)(ws + woff);
        k_front<<<NB_TR + NB_PW + npb, 256, 0, stream>>>(
            v0, v1, v2, v3, fbuf /*dummy*/, conv_w, lfc_w, fc2_w, fc3_w, fc4_w,
            w0f, w1f, w2f, w3f, w4f, x, hist, m);
        k_sample<false, false><<<nsb, 256, 0, stream>>>(x, nullptr, nullptr, fbuf, m, nsb);
        k_mlp<false><<<nb, 512, 0, stream>>>(x, fbuf, nullptr, w0f, conv_b, w1f, lfc_b,
                                             fc1_w, fc1_b, w2f, fc2_b, w3f, fc3_b,
                                             w4f, fc4_b, out, m);
    }
}